// Round 4
// baseline (707.046 us; speedup 1.0000x reference)
//
#include <hip/hip_runtime.h>
#include <hip/hip_bf16.h>

#define N_NODESC 100000
#define N_EDGESC 1000000
#define N_QUERYC 100000

typedef short short8 __attribute__((ext_vector_type(8)));
typedef float f32x4 __attribute__((ext_vector_type(4)));

// ---------- dual-dtype load helper (flag: 1 = inputs are bf16, 0 = f32) ----------
__device__ __forceinline__ float ldf(const void* p, int i, int isbf) {
  return isbf ? __bfloat162float(((const __hip_bfloat16*)p)[i])
              : ((const float*)p)[i];
}
__device__ __forceinline__ unsigned short f2b(float x) {
  __hip_bfloat16 h = __float2bfloat16(x);
  return *(unsigned short*)&h;
}
__device__ __forceinline__ float b2f(unsigned int u) {
  return __uint_as_float(u << 16);
}
__device__ __forceinline__ void gload16(const void* g, void* l) {
  __builtin_amdgcn_global_load_lds(
      (const __attribute__((address_space(1))) void*)g,
      (__attribute__((address_space(3))) void*)l, 16, 0, 0);
}

// ---------- 0: sniff input dtype ----------
__global__ void k_sniff(const void* x, int* flag) {
  __shared__ int cnt;
  int t = threadIdx.x;
  if (t == 0) cnt = 0;
  __syncthreads();
  const unsigned short* h = (const unsigned short*)x;
  int local = 0;
  for (int i = t; i < 4096; i += 256) {
    int e = (h[i] >> 7) & 0xFF;
    if (e >= 107 && e <= 133) local++;
  }
  atomicAdd(&cnt, local);
  __syncthreads();
  if (t == 0) *flag = (cnt >= 3482) ? 1 : 0;
}

// ---------- 1: histogram of dst ----------
__global__ void k_hist(const int* __restrict__ dst, int* __restrict__ cnt, int ne) {
  int e = blockIdx.x * 256 + threadIdx.x;
  if (e < ne) atomicAdd(&cnt[dst[e]], 1);
}

// ---------- 2a: per-chunk exclusive scan ----------
__global__ void k_scan1(const int* __restrict__ cnt, int* __restrict__ off,
                        int* __restrict__ partials, int n) {
  __shared__ int s[1024];
  int t = threadIdx.x;
  int idx = blockIdx.x * 1024 + t;
  int v = (idx < n) ? cnt[idx] : 0;
  s[t] = v;
  __syncthreads();
  for (int d = 1; d < 1024; d <<= 1) {
    int tmp = (t >= d) ? s[t - d] : 0;
    __syncthreads();
    s[t] += tmp;
    __syncthreads();
  }
  if (idx < n) off[idx] = s[t] - v;
  if (t == 1023) partials[blockIdx.x] = s[1023];
}

// ---------- 2b: scan chunk totals ----------
__global__ void k_scan2(const int* __restrict__ partials, int* __restrict__ pref,
                        int* __restrict__ off, int nb, int npos) {
  __shared__ int s[128];
  int t = threadIdx.x;
  int v = (t < nb) ? partials[t] : 0;
  s[t] = v;
  __syncthreads();
  for (int d = 1; d < 128; d <<= 1) {
    int tmp = (t >= d) ? s[t - d] : 0;
    __syncthreads();
    s[t] += tmp;
    __syncthreads();
  }
  if (t < nb) pref[t] = s[t] - v;
  if (t == 127) off[npos] = s[127];
}

// ---------- 2c: apply chunk prefixes ----------
__global__ void k_scan3(int* __restrict__ off, const int* __restrict__ pref,
                        int* __restrict__ cursor, int n) {
  int i = blockIdx.x * 256 + threadIdx.x;
  if (i < n) {
    int o = off[i] + pref[i >> 10];
    off[i] = o;
    cursor[i] = o;
  }
}

// ---------- 3: bucket fill (m = -norm, packed float4) ----------
__global__ void k_fill(const int* __restrict__ ei,
                       const void* nr, const void* ni, const void* nj, const void* nk,
                       const int* __restrict__ flagp, int* __restrict__ cursor,
                       int* __restrict__ srcS, float4* __restrict__ m4, int ne) {
  int isbf = *flagp;
  int e = blockIdx.x * 256 + threadIdx.x;
  if (e >= ne) return;
  int s = ei[e];
  int d = ei[ne + e];
  int pos = atomicAdd(&cursor[d], 1);
  srcS[pos] = s;
  float4 m;
  m.x = -ldf(nr, e, isbf);
  m.y = -ldf(ni, e, isbf);
  m.z = -ldf(nj, e, isbf);
  m.w = -ldf(nk, e, isbf);
  m4[pos] = m;
}

// ---------- 3b: interleave inputs -> Xg[node][feat][comp] bf16 ----------
__global__ __launch_bounds__(256) void k_ilv(
    const void* X0, const void* X1, const void* X2, const void* X3,
    const int* __restrict__ flagp, unsigned short* __restrict__ Xg, int n) {
  int isbf = *flagp;
  int lane = threadIdx.x & 63;
  int node = blockIdx.x * 4 + (threadIdx.x >> 6);
  if (node >= n) return;
  int idx = node * 64 + lane;
  unsigned int lo = f2b(ldf(X0, idx, isbf)) | ((unsigned int)f2b(ldf(X1, idx, isbf)) << 16);
  unsigned int hi = f2b(ldf(X2, idx, isbf)) | ((unsigned int)f2b(ldf(X3, idx, isbf)) << 16);
  uint2 g = make_uint2(lo, hi);
  *(uint2*)(Xg + (size_t)node * 256 + lane * 4) = g;
}

// ---------- 4: quaternion aggregation (wave per node) -> fragment-major Tf ----------
// Tf layout (shorts): Tf[(node>>4)*4096 + kc*512 + q*128 + (node&15)*8 + j]
//   = T_row(node)[k], k = kc*32 + q*8 + j  -- exactly MFMA A-frag order.
__global__ __launch_bounds__(256) void k_agg(
    const unsigned short* __restrict__ Xg, const int* __restrict__ off,
    const int* __restrict__ srcS, const float4* __restrict__ m4,
    unsigned short* __restrict__ Tf, int nnodes) {
  __shared__ unsigned short tl[4][256];
  int lane = threadIdx.x & 63;
  int w = threadIdx.x >> 6;
  int node = blockIdx.x * 4 + w;
  if (node >= nnodes) return;
  int rs = off[node], re = off[node + 1];
  float tr = 0.f, ti = 0.f, tj = 0.f, tk = 0.f;

  auto qacc = [&](uint2 g, float4 m) {
    float xr = b2f(g.x & 0xffffu), xi = b2f(g.x >> 16);
    float xj = b2f(g.y & 0xffffu), xk = b2f(g.y >> 16);
    tr += m.x * xr - m.y * xi - m.z * xj - m.w * xk;
    ti += m.x * xi + m.y * xr + m.z * xk - m.w * xj;
    tj += m.x * xj - m.y * xk + m.z * xr + m.w * xi;
    tk += m.x * xk + m.y * xj - m.z * xi + m.w * xr;
  };

  int e = rs;
  for (; e + 3 < re; e += 4) {
    int s0 = srcS[e], s1 = srcS[e + 1], s2 = srcS[e + 2], s3 = srcS[e + 3];
    float4 ma = m4[e], mb = m4[e + 1], mc = m4[e + 2], md = m4[e + 3];
    uint2 g0 = *(const uint2*)(Xg + (size_t)s0 * 256 + lane * 4);
    uint2 g1 = *(const uint2*)(Xg + (size_t)s1 * 256 + lane * 4);
    uint2 g2 = *(const uint2*)(Xg + (size_t)s2 * 256 + lane * 4);
    uint2 g3 = *(const uint2*)(Xg + (size_t)s3 * 256 + lane * 4);
    qacc(g0, ma); qacc(g1, mb); qacc(g2, mc); qacc(g3, md);
  }
  for (; e < re; ++e) {
    uint2 g0 = *(const uint2*)(Xg + (size_t)srcS[e] * 256 + lane * 4);
    qacc(g0, m4[e]);
  }

  // in-wave transpose: lane=f holds 4 comps -> 16B chunks in k-order
  tl[w][lane] = f2b(tr);
  tl[w][64 + lane] = f2b(ti);
  tl[w][128 + lane] = f2b(tj);
  tl[w][192 + lane] = f2b(tk);
  __builtin_amdgcn_wave_barrier();
  if (lane < 32) {
    uint4 v = *(const uint4*)&tl[w][lane * 8];
    size_t o = (size_t)(node >> 4) * 4096 + (lane >> 2) * 512 + (lane & 3) * 128 +
               (node & 15) * 8;
    *(uint4*)(Tf + o) = v;
  }
}

// ---------- 5: build Weff^T (K-major, bf16) + bias ----------
// Wt[col*256 + krow] = sign(a,c) * W[a^c][kk][h]; a=krow>>6,kk=krow&63,c=col>>6,h=col&63
__global__ void k_weff(const void* W, const void* b, const int* __restrict__ flagp,
                       unsigned short* __restrict__ Wt, float* __restrict__ bcat) {
  int isbf = *flagp;
  int t = blockIdx.x * 256 + threadIdx.x;
  int col = t >> 8;
  int krow = t & 255;
  int a = krow >> 6, kk = krow & 63, c = col >> 6, h = col & 63;
  int w = a ^ c;
  float sgn = ((0x3950 >> (a * 4 + c)) & 1) ? -1.f : 1.f;
  Wt[t] = f2b(sgn * ldf(W, w * 4096 + kk * 64 + h, isbf));
  if (t < 256) bcat[t] = ldf(b, t, isbf);
}

// ---------- 6: single-barrier MFMA GEMM  C = A(Mx256) @ Weff(256x256) + bias, relu ----------
// grid (M/128, 2); block 256 (4 waves). y tiles f in [y*32,y*32+32).
// B half (128 cols x 256 k) staged once to LDS (64KB, XOR-swizzled 16B chunks).
// A frags loaded straight from fragment-major Tf (1KB coalesced per frag).
// One __syncthreads total. Epilogue as before (mode 0 / mode 1).
__global__ __launch_bounds__(256) void k_gemm(
    const unsigned short* __restrict__ A, const unsigned short* __restrict__ Bw,
    const float* __restrict__ bias, int M, int mode,
    unsigned short* __restrict__ XgOut,
    float* __restrict__ P, const void* Cw, const int* __restrict__ flagp) {
  __shared__ unsigned short Bsm[32768];  // 64KB: 128 ct-rows x 32 chunks of 16B

  int t = threadIdx.x;
  int lane = t & 63;
  int w = t >> 6;
  int l15 = lane & 15, quad = lane >> 4;
  int m0 = blockIdx.x * 128;
  int y = blockIdx.y;

  // stage B: physical chunk p = i*256 + t; logical: ct=p>>5, s=(p&31)^(ct&7)
#pragma unroll
  for (int i = 0; i < 16; i++) {
    int p = i * 256 + t;
    int ct = p >> 5;
    int s = (p & 31) ^ (ct & 7);
    int col = (ct >> 5) * 64 + y * 32 + (ct & 31);
    gload16((const char*)Bw + (size_t)col * 512 + s * 16,
            (char*)Bsm + (size_t)(i * 256 + w * 64) * 16);
  }

  // A fragments: all 32 loads in flight (independent, fully coalesced)
  short8 av[4][8];
  int tbase = (m0 + (w >> 1) * 64) >> 4;
#pragma unroll
  for (int mi = 0; mi < 4; mi++)
#pragma unroll
    for (int kc = 0; kc < 8; kc++)
      av[mi][kc] = *(const short8*)(A + ((size_t)(tbase + mi) * 8 + kc) * 512 + lane * 8);

  __syncthreads();

  f32x4 acc[4][4];
#pragma unroll
  for (int mi = 0; mi < 4; mi++)
#pragma unroll
    for (int c = 0; c < 4; c++) acc[mi][c] = (f32x4){0.f, 0.f, 0.f, 0.f};

  int ctb = (w & 1) * 16 + l15;
#pragma unroll
  for (int kc = 0; kc < 8; kc++) {
    short8 bv[4];
#pragma unroll
    for (int c = 0; c < 4; c++) {
      int ct = c * 32 + ctb;
      int p = ct * 32 + ((kc * 4 + quad) ^ (ct & 7));
      bv[c] = *(const short8*)&Bsm[p * 8];
    }
#pragma unroll
    for (int mi = 0; mi < 4; mi++)
#pragma unroll
      for (int c = 0; c < 4; c++)
        acc[mi][c] = __builtin_amdgcn_mfma_f32_16x16x32_bf16(av[mi][kc], bv[c], acc[mi][c], 0, 0, 0);
  }

  int fl = y * 32 + (w & 1) * 16 + l15;
  float bias_v[4];
#pragma unroll
  for (int c = 0; c < 4; c++) bias_v[c] = bias[c * 64 + fl];

  if (mode == 0) {
#pragma unroll
    for (int mi = 0; mi < 4; mi++) {
#pragma unroll
      for (int r = 0; r < 4; r++) {
        int node = m0 + (w >> 1) * 64 + mi * 16 + quad * 4 + r;
        unsigned int lo = f2b(fmaxf(acc[mi][0][r] + bias_v[0], 0.f)) |
                          ((unsigned int)f2b(fmaxf(acc[mi][1][r] + bias_v[1], 0.f)) << 16);
        unsigned int hi = f2b(fmaxf(acc[mi][2][r] + bias_v[2], 0.f)) |
                          ((unsigned int)f2b(fmaxf(acc[mi][3][r] + bias_v[3], 0.f)) << 16);
        *(uint2*)(XgOut + (size_t)node * 256 + fl * 4) = make_uint2(lo, hi);
      }
    }
  } else {
    int isbf = *flagp;
    float cw[4][4];
#pragma unroll
    for (int c = 0; c < 4; c++)
#pragma unroll
      for (int d = 0; d < 2; d++)
#pragma unroll
        for (int e = 0; e < 2; e++)
          cw[c][e + 2 * d] = ldf(Cw, d * 512 + c * 128 + e * 64 + fl, isbf);
#pragma unroll
    for (int mi = 0; mi < 4; mi++) {
#pragma unroll
      for (int r = 0; r < 4; r++) {
        int node = m0 + (w >> 1) * 64 + mi * 16 + quad * 4 + r;
        float pd0 = 0.f, pd1 = 0.f, pd2 = 0.f, pd3 = 0.f;
#pragma unroll
        for (int c = 0; c < 4; c++) {
          float v = fmaxf(acc[mi][c][r] + bias_v[c], 0.f);
          pd0 += v * cw[c][0];
          pd1 += v * cw[c][1];
          pd2 += v * cw[c][2];
          pd3 += v * cw[c][3];
        }
#pragma unroll
        for (int o = 1; o < 16; o <<= 1) {
          pd0 += __shfl_xor(pd0, o);
          pd1 += __shfl_xor(pd1, o);
          pd2 += __shfl_xor(pd2, o);
          pd3 += __shfl_xor(pd3, o);
        }
        if (l15 == 0 && node < M) {
          atomicAdd(&P[node * 4 + 0], pd0);
          atomicAdd(&P[node * 4 + 1], pd1);
          atomicAdd(&P[node * 4 + 2], pd2);
          atomicAdd(&P[node * 4 + 3], pd3);
        }
      }
    }
  }
}

// ---------- 8: per-query logits + log_softmax ----------
__global__ void k_query(const int* __restrict__ qe, const float* __restrict__ P,
                        const void* Cb, const int* __restrict__ flagp,
                        void* out, int nq) {
  int isbf = *flagp;
  int q = blockIdx.x * 256 + threadIdx.x;
  if (q >= nq) return;
  int q0 = qe[q * 2], q1 = qe[q * 2 + 1];
  float l0 = P[q0 * 4 + 0] + P[q1 * 4 + 1] + ldf(Cb, 0, isbf);
  float l1 = P[q0 * 4 + 2] + P[q1 * 4 + 3] + ldf(Cb, 1, isbf);
  float m = fmaxf(l0, l1);
  float lse = m + logf(expf(l0 - m) + expf(l1 - m));
  float o0 = l0 - lse, o1 = l1 - lse;
  if (isbf) {
    __hip_bfloat16* o = (__hip_bfloat16*)out;
    o[q * 2] = __float2bfloat16(o0);
    o[q * 2 + 1] = __float2bfloat16(o1);
  } else {
    float* o = (float*)out;
    o[q * 2] = o0;
    o[q * 2 + 1] = o1;
  }
}

extern "C" void kernel_launch(void* const* d_in, const int* in_sizes, int n_in,
                              void* d_out, int out_size, void* d_ws, size_t ws_size,
                              hipStream_t stream) {
  const int N = N_NODESC, NE = N_EDGESC, NQ = N_QUERYC;
  const int NPAD = 100224;  // >= 782*128 = 100096

  char* w = (char*)d_ws;
  auto alloc = [&](size_t bytes) -> void* {
    void* p = (void*)w;
    w += (bytes + 255) & ~(size_t)255;
    return p;
  };
  int* flag       = (int*)alloc(4);
  int* offsets    = (int*)alloc((size_t)(N + 1) * 4);
  int* cursor     = (int*)alloc((size_t)N * 4);
  int* partials   = (int*)alloc(128 * 4);
  int* pref       = (int*)alloc(128 * 4);
  int* srcS       = (int*)alloc((size_t)NE * 4);
  float4* m4      = (float4*)alloc((size_t)NE * 16);
  unsigned short* Tf   = (unsigned short*)alloc((size_t)NPAD * 256 * 2);
  unsigned short* Xg   = (unsigned short*)alloc((size_t)NPAD * 256 * 2);
  unsigned short* Wt   = (unsigned short*)alloc(256 * 256 * 2);
  float* bcat     = (float*)alloc(256 * 4);
  float* P        = (float*)alloc((size_t)N * 4 * 4);
  (void)ws_size; (void)n_in; (void)in_sizes; (void)out_size;

  const int* ei = (const int*)d_in[8];

  k_sniff<<<1, 256, 0, stream>>>(d_in[0], flag);

  // CSR build
  hipMemsetAsync(cursor, 0, (size_t)N * 4, stream);
  hipMemsetAsync(P, 0, (size_t)N * 16, stream);
  k_hist<<<(NE + 255) / 256, 256, 0, stream>>>(ei + NE, cursor, NE);
  k_scan1<<<(N + 1023) / 1024, 1024, 0, stream>>>(cursor, offsets, partials, N);
  k_scan2<<<1, 128, 0, stream>>>(partials, pref, offsets, (N + 1023) / 1024, N);
  k_scan3<<<(N + 255) / 256, 256, 0, stream>>>(offsets, pref, cursor, N);
  k_fill<<<(NE + 255) / 256, 256, 0, stream>>>(ei, d_in[4], d_in[5], d_in[6], d_in[7],
                                               flag, cursor, srcS, m4, NE);

  // layer-1 gather source
  k_ilv<<<(N + 3) / 4, 256, 0, stream>>>(d_in[0], d_in[1], d_in[2], d_in[3], flag, Xg, N);

  dim3 ggrid((N + 127) / 128, 2);

  // layer 1
  k_agg<<<(N + 3) / 4, 256, 0, stream>>>(Xg, offsets, srcS, m4, Tf, N);
  k_weff<<<256, 256, 0, stream>>>(d_in[10], d_in[11], flag, Wt, bcat);
  k_gemm<<<ggrid, 256, 0, stream>>>(Tf, Wt, bcat, N, 0, Xg, nullptr, nullptr, flag);

  // layer 2 (+fused readout partial dots)
  k_agg<<<(N + 3) / 4, 256, 0, stream>>>(Xg, offsets, srcS, m4, Tf, N);
  k_weff<<<256, 256, 0, stream>>>(d_in[12], d_in[13], flag, Wt, bcat);
  k_gemm<<<ggrid, 256, 0, stream>>>(Tf, Wt, bcat, N, 1, nullptr, P, d_in[14], flag);

  // queries
  k_query<<<(NQ + 255) / 256, 256, 0, stream>>>((const int*)d_in[9], P, d_in[15],
                                                flag, d_out, NQ);
}